// Round 2
// baseline (473.966 us; speedup 1.0000x reference)
//
#include <hip/hip_runtime.h>
#include <cmath>

// Geometry: (B=2, C=1, Z=128, Y=256, X=256) fp32
#define NB 2
#define NZ 128
#define NY 256
#define NX 256
#define NPLANE (NY * NX)          // 65536
#define NVOL (NZ * NPLANE)        // 8388608
#define NTOT (NB * NVOL)          // 16777216

#define ZR 6                      // truncated z radius; dropped tail mass ~3.9e-5
#define C1F 1.0e-4f
#define C2F 9.0e-4f

struct Weights {
    float wz[2 * ZR + 1];         // 13 center taps of the 27-tap normalized kernel
    float wy[5];
    float wx[5];
};

// ---------------------------------------------------------------------------
// K1: z-blur of the 5 product fields for one 32-z substrip of one batch/chunk.
// Stages 44 zero-padded planes of a 64-wide x strip in LDS (22.5 KB), each
// warp register-blocks 8 z-outputs (window sharing: 20 LDS row-reads per
// thread produce 8 outputs x 5 fields). No border branches in the hot loop.
// ---------------------------------------------------------------------------
__global__ __launch_bounds__(256) void zblur_kernel(const float* __restrict__ A,
                                                    const float* __restrict__ B,
                                                    float* __restrict__ fields,
                                                    size_t fieldStride,   // CZ*NPLANE
                                                    int b, int zchunk0,
                                                    Weights W)
{
    const int x0 = blockIdx.x * 64;
    const int y  = blockIdx.y;
    const int zs = zchunk0 + blockIdx.z * 32;     // substrip base, global z

    __shared__ float As[44][64];
    __shared__ float Bs[44][64];

    const size_t basein = (size_t)b * NVOL + (size_t)y * NX + x0;

    // Stage planes zs-6 .. zs+37 (zero outside the volume), float4 vectorized.
    for (int i = threadIdx.x; i < 44 * 16; i += 256) {
        int r = i >> 4, c = (i & 15) << 2;
        int z = zs - ZR + r;
        float4 va = make_float4(0.f, 0.f, 0.f, 0.f);
        float4 vb = va;
        if (z >= 0 && z < NZ) {
            va = *reinterpret_cast<const float4*>(A + basein + (size_t)z * NPLANE + c);
            vb = *reinterpret_cast<const float4*>(B + basein + (size_t)z * NPLANE + c);
        }
        *reinterpret_cast<float4*>(&As[r][c]) = va;
        *reinterpret_cast<float4*>(&Bs[r][c]) = vb;
    }
    __syncthreads();

    const int x = threadIdx.x & 63;
    const int w = threadIdx.x >> 6;               // warp 0..3 -> z-outputs w*8..w*8+7

    float acc[8][5];
    #pragma unroll
    for (int j = 0; j < 8; ++j)
        #pragma unroll
        for (int f = 0; f < 5; ++f) acc[j][f] = 0.f;

    #pragma unroll
    for (int k = 0; k < 20; ++k) {                // LDS rows w*8 .. w*8+19
        int row = w * 8 + k;
        float a  = As[row][x];
        float bb = Bs[row][x];
        float aa = a * a, b2 = bb * bb, ab = a * bb;
        #pragma unroll
        for (int j = 0; j < 8; ++j) {
            const int t = k - j;                  // compile-time weight index
            if (t >= 0 && t <= 2 * ZR) {
                float wt = W.wz[t];
                acc[j][0] = fmaf(wt, a,  acc[j][0]);
                acc[j][1] = fmaf(wt, bb, acc[j][1]);
                acc[j][2] = fmaf(wt, aa, acc[j][2]);
                acc[j][3] = fmaf(wt, b2, acc[j][3]);
                acc[j][4] = fmaf(wt, ab, acc[j][4]);
            }
        }
    }

    const int zcbase = blockIdx.z * 32 + w * 8;   // chunk-relative z
    #pragma unroll
    for (int j = 0; j < 8; ++j) {
        size_t o = (size_t)(zcbase + j) * NPLANE + (size_t)y * NX + x0 + x;
        #pragma unroll
        for (int f = 0; f < 5; ++f)
            fields[(size_t)f * fieldStride + o] = acc[j][f];
    }
}

// ---------------------------------------------------------------------------
// K2: fused y-blur + x-blur + SSIM + mean-reduction over one plane tile.
// Block = 32x32 tile of one chunk-relative plane. Per field: stage 36x36
// (halo 2, zero-padded), y-blur to [32][36], x-blur to 4 regs/thread.
// ---------------------------------------------------------------------------
__global__ __launch_bounds__(256) void yx_ssim_kernel(const float* __restrict__ F,
                                                      size_t fieldStride,
                                                      float* __restrict__ acc_out,
                                                      Weights W)
{
    const int x0 = blockIdx.x * 32;
    const int y0 = blockIdx.y * 32;
    const int zc = blockIdx.z;
    const float* base = F + (size_t)zc * NPLANE;

    __shared__ float S[36][40];
    __shared__ float T[32][40];

    float res[5][4];

    #pragma unroll
    for (int f = 0; f < 5; ++f) {
        const float* src = base + (size_t)f * fieldStride;

        for (int i = threadIdx.x; i < 36 * 36; i += 256) {
            int r = i / 36, c = i - r * 36;
            int yy = y0 - 2 + r, xx = x0 - 2 + c;
            float v = 0.f;
            if ((unsigned)yy < NY && (unsigned)xx < NX)
                v = src[(size_t)yy * NX + xx];
            S[r][c] = v;
        }
        __syncthreads();

        for (int i = threadIdx.x; i < 32 * 36; i += 256) {
            int r = i / 36, c = i - r * 36;
            float v = 0.f;
            #pragma unroll
            for (int j = 0; j < 5; ++j) v = fmaf(W.wy[j], S[r + j][c], v);
            T[r][c] = v;
        }
        __syncthreads();

        #pragma unroll
        for (int p = 0; p < 4; ++p) {
            int i = threadIdx.x + p * 256;
            int r = i >> 5, c = i & 31;
            float v = 0.f;
            #pragma unroll
            for (int j = 0; j < 5; ++j) v = fmaf(W.wx[j], T[r][c + j], v);
            res[f][p] = v;
        }
        __syncthreads();
    }

    float local = 0.f;
    #pragma unroll
    for (int p = 0; p < 4; ++p) {
        float mu1 = res[0][p], mu2 = res[1][p];
        float z11 = res[2][p], z22 = res[3][p], z12 = res[4][p];
        float mu1sq = mu1 * mu1, mu2sq = mu2 * mu2, mu12 = mu1 * mu2;
        float num = (2.f * mu12 + C1F) * (2.f * (z12 - mu12) + C2F);
        float den = (mu1sq + mu2sq + C1F) * ((z11 - mu1sq) + (z22 - mu2sq) + C2F);
        local += num / den;
    }

    #pragma unroll
    for (int off = 32; off; off >>= 1)
        local += __shfl_down(local, off, 64);

    __shared__ float wsum[4];
    int lane = threadIdx.x & 63, wid = threadIdx.x >> 6;
    if (lane == 0) wsum[wid] = local;
    __syncthreads();
    if (threadIdx.x == 0)
        atomicAdd(acc_out, wsum[0] + wsum[1] + wsum[2] + wsum[3]);
}

__global__ void zero_kernel(float* p) { *p = 0.f; }

__global__ void finalize_kernel(const float* __restrict__ acc, float* __restrict__ out)
{
    out[0] = 1.0f - acc[0] * (1.0f / (float)NTOT);
}

// ---------------------------------------------------------------------------
extern "C" void kernel_launch(void* const* d_in, const int* in_sizes, int n_in,
                              void* d_out, int out_size, void* d_ws, size_t ws_size,
                              hipStream_t stream)
{
    const float* img1 = (const float*)d_in[0];
    const float* img2 = (const float*)d_in[1];
    float* out = (float*)d_out;

    // ws layout: [acc (64 B pad)] [5 fields of CZ*NPLANE floats]
    // CZ adapts to ws_size; CZ=32 needs ~42 MB.
    int CZ = 128;
    while (CZ > 32 && 64 + 5ull * CZ * NPLANE * 4ull > ws_size) CZ >>= 1;

    float* acc    = (float*)d_ws;
    float* fields = (float*)((char*)d_ws + 64);
    const size_t fieldStride = (size_t)CZ * NPLANE;

    Weights W;
    {
        double gz[27], sz = 0.0;
        for (int i = 0; i < 27; ++i) { double d = i - 13; gz[i] = exp(-d * d / 4.5); sz += gz[i]; }
        for (int k = -ZR; k <= ZR; ++k) W.wz[k + ZR] = (float)(gz[k + 13] / sz);
        double gy[5], sy = 0.0;
        for (int i = 0; i < 5; ++i) { double d = i - 2; gy[i] = exp(-d * d / 4.5); sy += gy[i]; }
        for (int i = 0; i < 5; ++i) { W.wy[i] = (float)(gy[i] / sy); W.wx[i] = (float)(gy[i] / sy); }
    }

    zero_kernel<<<1, 1, 0, stream>>>(acc);

    for (int b = 0; b < NB; ++b) {
        for (int z0 = 0; z0 < NZ; z0 += CZ) {
            dim3 g1(NX / 64, NY, CZ / 32);
            zblur_kernel<<<g1, 256, 0, stream>>>(img1, img2, fields, fieldStride, b, z0, W);
            dim3 g2(NX / 32, NY / 32, CZ);
            yx_ssim_kernel<<<g2, 256, 0, stream>>>(fields, fieldStride, acc, W);
        }
    }

    finalize_kernel<<<1, 1, 0, stream>>>(acc, out);
}

// Round 3
// 335.750 us; speedup vs baseline: 1.4117x; 1.4117x over previous
//
#include <hip/hip_runtime.h>
#include <hip/hip_fp16.h>
#include <cmath>

// Geometry: (B=2, C=1, Z=128, Y=256, X=256) fp32 in, scalar f32 out
#define NB 2
#define NZ 128
#define NY 256
#define NX 256
#define NPLANE (NY * NX)          // 65536
#define NVOL (NZ * NPLANE)        // 8388608
#define NTOT (NB * NVOL)          // 16777216

#define ZR 6                      // truncated z radius; dropped tail mass ~1e-5
#define C1F 1.0e-4f
#define C2F 9.0e-4f

#define TY 32
#define TX 64

struct Weights {
    float wz[2 * ZR + 1];
    float wy[5];
    float wx[5];
};

// ---------------------------------------------------------------------------
// K1: z-blur of the 5 product fields -> fp16 workspace.
// Block = (64-x strip, y row, 32-z substrip). Reg-buffered staging (6 float4
// loads in flight), LDS 44x64 per image, 8 z-outputs per thread via window
// sharing. Stores __half (halves intermediate HBM traffic).
// ---------------------------------------------------------------------------
__global__ __launch_bounds__(256, 4) void zblur_kernel(const float* __restrict__ A,
                                                       const float* __restrict__ B,
                                                       __half* __restrict__ fields,
                                                       size_t fieldStride,   // CZ*NPLANE halfs
                                                       int b, int zchunk0,
                                                       Weights W)
{
    const int x0 = blockIdx.x * 64;
    const int y  = blockIdx.y;
    const int zs = zchunk0 + blockIdx.z * 32;

    __shared__ float As[44][64];
    __shared__ float Bs[44][64];

    const size_t basein = (size_t)b * NVOL + (size_t)y * NX + x0;

    // Stage planes zs-6 .. zs+37 (zero outside volume). 704 float4 slots per
    // image; reg-buffer so all 6 loads per thread are in flight together.
    float4 va[3], vb[3];
    #pragma unroll
    for (int k = 0; k < 3; ++k) {
        int i = threadIdx.x + k * 256;
        va[k] = make_float4(0.f, 0.f, 0.f, 0.f);
        vb[k] = va[k];
        if (i < 704) {
            int r = i >> 4, c = (i & 15) << 2;
            int z = zs - ZR + r;
            if (z >= 0 && z < NZ) {
                va[k] = *reinterpret_cast<const float4*>(A + basein + (size_t)z * NPLANE + c);
                vb[k] = *reinterpret_cast<const float4*>(B + basein + (size_t)z * NPLANE + c);
            }
        }
    }
    #pragma unroll
    for (int k = 0; k < 3; ++k) {
        int i = threadIdx.x + k * 256;
        if (i < 704) {
            int r = i >> 4, c = (i & 15) << 2;
            *reinterpret_cast<float4*>(&As[r][c]) = va[k];
            *reinterpret_cast<float4*>(&Bs[r][c]) = vb[k];
        }
    }
    __syncthreads();

    const int x = threadIdx.x & 63;
    const int w = threadIdx.x >> 6;               // warp 0..3 -> z outs w*8..w*8+7

    float acc[8][5];
    #pragma unroll
    for (int j = 0; j < 8; ++j)
        #pragma unroll
        for (int f = 0; f < 5; ++f) acc[j][f] = 0.f;

    #pragma unroll
    for (int k = 0; k < 20; ++k) {                // LDS rows w*8 .. w*8+19
        int row = w * 8 + k;
        float a  = As[row][x];
        float bb = Bs[row][x];
        float aa = a * a, b2 = bb * bb, ab = a * bb;
        #pragma unroll
        for (int j = 0; j < 8; ++j) {
            const int t = k - j;                  // compile-time weight index
            if (t >= 0 && t <= 2 * ZR) {
                float wt = W.wz[t];
                acc[j][0] = fmaf(wt, a,  acc[j][0]);
                acc[j][1] = fmaf(wt, bb, acc[j][1]);
                acc[j][2] = fmaf(wt, aa, acc[j][2]);
                acc[j][3] = fmaf(wt, b2, acc[j][3]);
                acc[j][4] = fmaf(wt, ab, acc[j][4]);
            }
        }
    }

    const int zcbase = blockIdx.z * 32 + w * 8;   // chunk-relative z
    #pragma unroll
    for (int j = 0; j < 8; ++j) {
        size_t o = (size_t)(zcbase + j) * NPLANE + (size_t)y * NX + x0 + x;
        #pragma unroll
        for (int f = 0; f < 5; ++f)
            fields[(size_t)f * fieldStride + o] = __float2half_rn(acc[j][f]);
    }
}

// ---------------------------------------------------------------------------
// K2: fused y-blur + x-blur + SSIM + reduction. Tile 64x32 outputs.
// One staging pass for ALL 5 fields (24-deep reg-buffered loads -> full MLP),
// 3 barriers total. fp16 LDS; fp32 math.
// ---------------------------------------------------------------------------
__global__ __launch_bounds__(256, 3) void yx_ssim_kernel(const __half* __restrict__ F,
                                                         size_t fieldStride,
                                                         float* __restrict__ acc_out,
                                                         Weights W)
{
    const int x0 = blockIdx.x * TX;
    const int y0 = blockIdx.y * TY;
    const int zc = blockIdx.z;

    __shared__ __half Sh[5][36][68];   // 24480 B: staged fields, halo 2 (zero pad)
    __shared__ __half T[5][32][72];    // 23040 B: y-blurred

    // ---- stage: 5 fields x 36 rows x 34 half-pairs = 6120 dword loads ----
    unsigned vbuf[24];
    int      abuf[24];
    #pragma unroll
    for (int k = 0; k < 24; ++k) {
        int i = threadIdx.x + k * 256;
        unsigned v = 0; int addr = -1;
        if (i < 6120) {
            int f  = i / 1224;
            int r2 = i - f * 1224;
            int r  = r2 / 34;
            int c2 = r2 - r * 34;
            int yy = y0 - 2 + r;
            int xx = x0 - 2 + c2 * 2;          // even; invalid pairs are pair-aligned
            if ((unsigned)yy < NY && (unsigned)xx < NX)
                v = *reinterpret_cast<const unsigned*>(
                        F + (size_t)f * fieldStride + (size_t)zc * NPLANE
                          + (size_t)yy * NX + xx);
            addr = (f * 36 + r) * 68 + c2 * 2;
        }
        vbuf[k] = v; abuf[k] = addr;
    }
    __half* shflat = &Sh[0][0][0];
    #pragma unroll
    for (int k = 0; k < 24; ++k)
        if (abuf[k] >= 0)
            *reinterpret_cast<unsigned*>(shflat + abuf[k]) = vbuf[k];
    __syncthreads();

    // ---- y-blur: 5 fields x 32 rows x 17 quads (b64 in, b64 out) ----
    for (int i = threadIdx.x; i < 2720; i += 256) {
        int f  = i / 544;
        int r2 = i - f * 544;
        int yo = r2 / 17;
        int cq = r2 - yo * 17;
        int c  = cq * 4;
        float s0 = 0.f, s1 = 0.f, s2 = 0.f, s3 = 0.f;
        #pragma unroll
        for (int d = 0; d < 5; ++d) {
            const __half2* p = reinterpret_cast<const __half2*>(&Sh[f][yo + d][c]);
            float2 u0 = __half22float2(p[0]);
            float2 u1 = __half22float2(p[1]);
            float wt = W.wy[d];
            s0 = fmaf(wt, u0.x, s0); s1 = fmaf(wt, u0.y, s1);
            s2 = fmaf(wt, u1.x, s2); s3 = fmaf(wt, u1.y, s3);
        }
        __half2* q = reinterpret_cast<__half2*>(&T[f][yo][c]);
        q[0] = __floats2half2_rn(s0, s1);
        q[1] = __floats2half2_rn(s2, s3);
    }
    __syncthreads();

    // ---- x-blur + SSIM: thread = (row ty, 8-wide x run) ----
    const int ty = threadIdx.x >> 3;          // 0..31
    const int xs = (threadIdx.x & 7) * 8;     // 0..56

    float vals[5][12];
    #pragma unroll
    for (int f = 0; f < 5; ++f) {
        const __half2* p = reinterpret_cast<const __half2*>(&T[f][ty][xs]);
        #pragma unroll
        for (int k2 = 0; k2 < 6; ++k2) {
            float2 u = __half22float2(p[k2]);
            vals[f][2 * k2]     = u.x;
            vals[f][2 * k2 + 1] = u.y;
        }
    }

    float local = 0.f;
    #pragma unroll
    for (int k = 0; k < 8; ++k) {
        float r[5];
        #pragma unroll
        for (int f = 0; f < 5; ++f) {
            float s = 0.f;
            #pragma unroll
            for (int d = 0; d < 5; ++d)
                s = fmaf(W.wx[d], vals[f][k + d], s);
            r[f] = s;
        }
        float mu1 = r[0], mu2 = r[1], z11 = r[2], z22 = r[3], z12 = r[4];
        float mu1sq = mu1 * mu1, mu2sq = mu2 * mu2, mu12 = mu1 * mu2;
        float num = (2.f * mu12 + C1F) * (2.f * (z12 - mu12) + C2F);
        float den = (mu1sq + mu2sq + C1F) * ((z11 - mu1sq) + (z22 - mu2sq) + C2F);
        local += __fdividef(num, den);
    }

    #pragma unroll
    for (int off = 32; off; off >>= 1)
        local += __shfl_down(local, off, 64);

    __shared__ float wsum[4];
    int lane = threadIdx.x & 63, wid = threadIdx.x >> 6;
    if (lane == 0) wsum[wid] = local;
    __syncthreads();
    if (threadIdx.x == 0)
        atomicAdd(acc_out, wsum[0] + wsum[1] + wsum[2] + wsum[3]);
}

__global__ void zero_kernel(float* p) { *p = 0.f; }

__global__ void finalize_kernel(const float* __restrict__ acc, float* __restrict__ out)
{
    out[0] = 1.0f - acc[0] * (1.0f / (float)NTOT);
}

// ---------------------------------------------------------------------------
extern "C" void kernel_launch(void* const* d_in, const int* in_sizes, int n_in,
                              void* d_out, int out_size, void* d_ws, size_t ws_size,
                              hipStream_t stream)
{
    const float* img1 = (const float*)d_in[0];
    const float* img2 = (const float*)d_in[1];
    float* out = (float*)d_out;

    // ws: [acc pad 64B][5 fp16 fields of CZ*NPLANE]; CZ=128 needs ~168 MB.
    int CZ = 128;
    while (CZ > 32 && 64 + 5ull * CZ * NPLANE * 2ull > ws_size) CZ >>= 1;

    float*  acc    = (float*)d_ws;
    __half* fields = (__half*)((char*)d_ws + 64);
    const size_t fieldStride = (size_t)CZ * NPLANE;

    Weights W;
    {
        double gz[27], sz = 0.0;
        for (int i = 0; i < 27; ++i) { double d = i - 13; gz[i] = exp(-d * d / 4.5); sz += gz[i]; }
        for (int k = -ZR; k <= ZR; ++k) W.wz[k + ZR] = (float)(gz[k + 13] / sz);
        double gy[5], sy = 0.0;
        for (int i = 0; i < 5; ++i) { double d = i - 2; gy[i] = exp(-d * d / 4.5); sy += gy[i]; }
        for (int i = 0; i < 5; ++i) { W.wy[i] = (float)(gy[i] / sy); W.wx[i] = (float)(gy[i] / sy); }
    }

    zero_kernel<<<1, 1, 0, stream>>>(acc);

    for (int b = 0; b < NB; ++b) {
        for (int z0 = 0; z0 < NZ; z0 += CZ) {
            dim3 g1(NX / 64, NY, CZ / 32);
            zblur_kernel<<<g1, 256, 0, stream>>>(img1, img2, fields, fieldStride, b, z0, W);
            dim3 g2(NX / TX, NY / TY, CZ);
            yx_ssim_kernel<<<g2, 256, 0, stream>>>(fields, fieldStride, acc, W);
        }
    }

    finalize_kernel<<<1, 1, 0, stream>>>(acc, out);
}

// Round 4
// 284.644 us; speedup vs baseline: 1.6651x; 1.1795x over previous
//
#include <hip/hip_runtime.h>
#include <hip/hip_fp16.h>
#include <cmath>

// Geometry: (B=2, C=1, Z=128, Y=256, X=256) fp32 in, scalar f32 out
#define NB 2
#define NZ 128
#define NY 256
#define NX 256
#define NPLANE (NY * NX)          // 65536
#define NVOL (NZ * NPLANE)        // 8388608
#define NTOT (NB * NVOL)          // 16777216

#define ZR 6                      // truncated z radius; dropped tail mass ~1e-5
#define C1F 1.0e-4f
#define C2F 9.0e-4f

struct Weights {
    float wz[2 * ZR + 1];         // 13 center taps of normalized 27-tap kernel
    float wy[5];
    float wx[5];
};

// ---------------------------------------------------------------------------
// K1: z-blur of the 5 product fields -> fp16 workspace.
// Block = (64-x strip, y row), FULL z column staged as fp16 in LDS with a
// 6-plane zero pad on each end (140 planes, 35.8 KB total -> 4 blocks/CU).
// No z-halo HBM re-read, branch-free hot loop. Warp w covers z-groups
// {w,w+4,w+8,w+12}, 8 z-outputs per group via window sharing.
// ---------------------------------------------------------------------------
__global__ __launch_bounds__(256) void zblur_kernel(const float* __restrict__ A,
                                                    const float* __restrict__ B,
                                                    __half* __restrict__ fields,
                                                    size_t fieldStride,   // CZ*NPLANE halfs
                                                    int b, int zc0, int CZ,
                                                    Weights W)
{
    const int x0 = blockIdx.x * 64;
    const int y  = blockIdx.y;

    __shared__ __half As[140][64];    // rows r: z = r-6, zero-padded
    __shared__ __half Bs[140][64];

    const size_t basein = (size_t)b * NVOL + (size_t)y * NX + x0;

    // Stage 140 rows x 16 float4 per image = 2240 slots.
    #pragma unroll
    for (int k = 0; k < 9; ++k) {
        int i = threadIdx.x + k * 256;
        if (i < 2240) {
            int r = i >> 4, c = (i & 15) << 2;
            int z = r - ZR;
            float4 va = make_float4(0.f, 0.f, 0.f, 0.f), vb = va;
            if ((unsigned)z < NZ) {
                va = *reinterpret_cast<const float4*>(A + basein + (size_t)z * NPLANE + c);
                vb = *reinterpret_cast<const float4*>(B + basein + (size_t)z * NPLANE + c);
            }
            *reinterpret_cast<__half2*>(&As[r][c])     = __floats2half2_rn(va.x, va.y);
            *reinterpret_cast<__half2*>(&As[r][c + 2]) = __floats2half2_rn(va.z, va.w);
            *reinterpret_cast<__half2*>(&Bs[r][c])     = __floats2half2_rn(vb.x, vb.y);
            *reinterpret_cast<__half2*>(&Bs[r][c + 2]) = __floats2half2_rn(vb.z, vb.w);
        }
    }
    __syncthreads();

    const int x = threadIdx.x & 63;
    const int w = threadIdx.x >> 6;

    for (int gi = 0; gi < 4; ++gi) {
        const int z0 = (w + gi * 4) * 8;          // output group z0..z0+7
        float acc[8][5];
        #pragma unroll
        for (int j = 0; j < 8; ++j)
            #pragma unroll
            for (int f = 0; f < 5; ++f) acc[j][f] = 0.f;

        #pragma unroll
        for (int k = 0; k < 20; ++k) {            // padded rows z0 .. z0+19
            int row = z0 + k;
            float a  = __half2float(As[row][x]);
            float bb = __half2float(Bs[row][x]);
            float aa = a * a, b2 = bb * bb, ab = a * bb;
            #pragma unroll
            for (int j = 0; j < 8; ++j) {
                const int t = k - j;              // compile-time weight index
                if (t >= 0 && t <= 2 * ZR) {
                    float wt = W.wz[t];
                    acc[j][0] = fmaf(wt, a,  acc[j][0]);
                    acc[j][1] = fmaf(wt, bb, acc[j][1]);
                    acc[j][2] = fmaf(wt, aa, acc[j][2]);
                    acc[j][3] = fmaf(wt, b2, acc[j][3]);
                    acc[j][4] = fmaf(wt, ab, acc[j][4]);
                }
            }
        }

        #pragma unroll
        for (int j = 0; j < 8; ++j) {
            int zr = z0 + j - zc0;                // chunk-relative z
            if (zr >= 0 && zr < CZ) {
                size_t o = (size_t)zr * NPLANE + (size_t)y * NX + x0 + x;
                #pragma unroll
                for (int f = 0; f < 5; ++f)
                    fields[(size_t)f * fieldStride + o] = __float2half_rn(acc[j][f]);
            }
        }
    }
}

// ---------------------------------------------------------------------------
// K2: LDS-free fused y-blur + x-blur + SSIM + reduction.
// Thread owns 2 consecutive rows x 8 x-cols of one plane. Per field: 6
// predicated b128 tap-row loads straight from HBM (L1/L2 absorbs the 5x
// vertical reuse), fp32 y-blur in regs, x-halo via shfl, x-blur + SSIM.
// No barriers except the final 4-word reduction.
// ---------------------------------------------------------------------------
__global__ __launch_bounds__(256) void yx_ssim_kernel(const __half* __restrict__ F,
                                                      size_t fieldStride,
                                                      float* __restrict__ acc_out,
                                                      Weights W)
{
    const int strip = blockIdx.x;             // 16 y-strips of 16 rows
    const int zc    = blockIdx.y;             // chunk-relative plane
    const int tid   = threadIdx.x;
    const int lx    = tid & 31;               // x-subtile 0..31
    const int xs    = lx * 8;
    const int y0    = strip * 16 + (tid >> 5) * 2;   // this thread's first row

    const __half* base = F + (size_t)zc * NPLANE;

    float res[5][2][8];

    #pragma unroll
    for (int f = 0; f < 5; ++f) {
        const __half* src = base + (size_t)f * fieldStride;

        // 6 tap rows (y0-2 .. y0+3), zero outside image
        uint4 h[6];
        #pragma unroll
        for (int d = 0; d < 6; ++d) {
            int yy = y0 - 2 + d;
            uint4 v = make_uint4(0u, 0u, 0u, 0u);
            if ((unsigned)yy < NY)
                v = *reinterpret_cast<const uint4*>(src + (size_t)yy * NX + xs);
            h[d] = v;
        }

        // y-blur for rows y0 (T0: taps d=0..4) and y0+1 (T1: taps d=1..5)
        float T0[8], T1[8];
        #pragma unroll
        for (int j = 0; j < 8; ++j) { T0[j] = 0.f; T1[j] = 0.f; }
        #pragma unroll
        for (int d = 0; d < 6; ++d) {
            const __half2* ph = reinterpret_cast<const __half2*>(&h[d]);
            float v[8];
            #pragma unroll
            for (int q = 0; q < 4; ++q) {
                float2 u = __half22float2(ph[q]);
                v[2 * q] = u.x; v[2 * q + 1] = u.y;
            }
            if (d < 5) {
                float wt = W.wy[d];
                #pragma unroll
                for (int j = 0; j < 8; ++j) T0[j] = fmaf(wt, v[j], T0[j]);
            }
            if (d > 0) {
                float wt = W.wy[d - 1];
                #pragma unroll
                for (int j = 0; j < 8; ++j) T1[j] = fmaf(wt, v[j], T1[j]);
            }
        }

        // x halo from neighbor lanes (cols xs-2,xs-1,xs+8,xs+9); zero at borders
        #pragma unroll
        for (int r = 0; r < 2; ++r) {
            float* T = r ? T1 : T0;
            float sm2 = __shfl_up(T[6], 1, 64);
            float sm1 = __shfl_up(T[7], 1, 64);
            float sp8 = __shfl_down(T[0], 1, 64);
            float sp9 = __shfl_down(T[1], 1, 64);
            float e[12];
            e[0]  = (lx == 0)  ? 0.f : sm2;
            e[1]  = (lx == 0)  ? 0.f : sm1;
            #pragma unroll
            for (int j = 0; j < 8; ++j) e[2 + j] = T[j];
            e[10] = (lx == 31) ? 0.f : sp8;
            e[11] = (lx == 31) ? 0.f : sp9;
            #pragma unroll
            for (int j = 0; j < 8; ++j) {
                float s = 0.f;
                #pragma unroll
                for (int i = 0; i < 5; ++i) s = fmaf(W.wx[i], e[j + i], s);
                res[f][r][j] = s;
            }
        }
    }

    float local = 0.f;
    #pragma unroll
    for (int r = 0; r < 2; ++r)
        #pragma unroll
        for (int j = 0; j < 8; ++j) {
            float mu1 = res[0][r][j], mu2 = res[1][r][j];
            float z11 = res[2][r][j], z22 = res[3][r][j], z12 = res[4][r][j];
            float mu1sq = mu1 * mu1, mu2sq = mu2 * mu2, mu12 = mu1 * mu2;
            float num = (2.f * mu12 + C1F) * (2.f * (z12 - mu12) + C2F);
            float den = (mu1sq + mu2sq + C1F) * ((z11 - mu1sq) + (z22 - mu2sq) + C2F);
            local += __fdividef(num, den);
        }

    #pragma unroll
    for (int off = 32; off; off >>= 1)
        local += __shfl_down(local, off, 64);

    __shared__ float wsum[4];
    int lane = tid & 63, wid = tid >> 6;
    if (lane == 0) wsum[wid] = local;
    __syncthreads();
    if (tid == 0)
        atomicAdd(acc_out, wsum[0] + wsum[1] + wsum[2] + wsum[3]);
}

__global__ void zero_kernel(float* p) { *p = 0.f; }

__global__ void finalize_kernel(const float* __restrict__ acc, float* __restrict__ out)
{
    out[0] = 1.0f - acc[0] * (1.0f / (float)NTOT);
}

// ---------------------------------------------------------------------------
extern "C" void kernel_launch(void* const* d_in, const int* in_sizes, int n_in,
                              void* d_out, int out_size, void* d_ws, size_t ws_size,
                              hipStream_t stream)
{
    const float* img1 = (const float*)d_in[0];
    const float* img2 = (const float*)d_in[1];
    float* out = (float*)d_out;

    // ws: [acc pad 64B][5 fp16 fields of CZ*NPLANE]; CZ=128 needs ~84 MB.
    int CZ = 128;
    while (CZ > 32 && 64 + 5ull * CZ * NPLANE * 2ull > ws_size) CZ >>= 1;

    float*  acc    = (float*)d_ws;
    __half* fields = (__half*)((char*)d_ws + 64);
    const size_t fieldStride = (size_t)CZ * NPLANE;

    Weights W;
    {
        double gz[27], sz = 0.0;
        for (int i = 0; i < 27; ++i) { double d = i - 13; gz[i] = exp(-d * d / 4.5); sz += gz[i]; }
        for (int k = -ZR; k <= ZR; ++k) W.wz[k + ZR] = (float)(gz[k + 13] / sz);
        double gy[5], sy = 0.0;
        for (int i = 0; i < 5; ++i) { double d = i - 2; gy[i] = exp(-d * d / 4.5); sy += gy[i]; }
        for (int i = 0; i < 5; ++i) { W.wy[i] = (float)(gy[i] / sy); W.wx[i] = (float)(gy[i] / sy); }
    }

    zero_kernel<<<1, 1, 0, stream>>>(acc);

    for (int b = 0; b < NB; ++b) {
        for (int z0 = 0; z0 < NZ; z0 += CZ) {
            dim3 g1(NX / 64, NY);
            zblur_kernel<<<g1, 256, 0, stream>>>(img1, img2, fields, fieldStride, b, z0, CZ, W);
            dim3 g2(NY / 16, CZ);
            yx_ssim_kernel<<<g2, 256, 0, stream>>>(fields, fieldStride, acc, W);
        }
    }

    finalize_kernel<<<1, 1, 0, stream>>>(acc, out);
}